// Round 4
// baseline (831.110 us; speedup 1.0000x reference)
//
#include <hip/hip_runtime.h>
#include <stdint.h>

// Attention_45148696216940: B=4, C=256, H=W=64 -> N=4096
// softmax over axis=1 (i), i.e. column softmax of S[i,j].
// Pipeline (bf16 MFMA 16x16x32, fp32 accum), NO global atomics anywhere:
//   kw: one-shot weight conversion: WQ=bf16(wq)/16, WK, WV, WPh/WPl (hi/lo split)
//   k0: X[b,c,n] f32 -> XT[b,n,c] bf16
//   k1: QT=(X Wq^T)/16+..., KT, V (bf16)
//   k2: Lp[isplit][b][j] = partial sum_i exp(S[i,j]-12)  (plain stores, 4 slices)
//   k2b: V[c,j] /= sum_s Lp[s][b][j]
//   k3: per block: one 16-i tile x ALL 4096 j; recompute S^T, P=exp(s-12),
//       PV accumulate in regs, direct f32x4 stores to OT (jsplit=1 -> no atomics)
//   k4: out = Wp . O + bp with split-bf16 (hi/lo)
//
// MFMA conventions: A row m = lane&15, B col n = lane&15, k = 32*cc + 8*(lane>>4) + e
// C/D: col = lane&15, row = 4*(lane>>4) + reg

#define DI __device__ __forceinline__
typedef __attribute__((ext_vector_type(4))) float f32x4;
typedef __attribute__((ext_vector_type(8))) short s16x8;
typedef __attribute__((ext_vector_type(4))) short s16x4;
typedef __attribute__((ext_vector_type(4))) unsigned short u16x4;

constexpr int C = 256;
constexpr int N = 4096;

DI unsigned short f2bf(float f) {
  unsigned int u = __float_as_uint(f);
  u += 0x7FFFu + ((u >> 16) & 1u);   // RNE
  return (unsigned short)(u >> 16);
}
DI float bf2f(unsigned short s) { return __uint_as_float(((unsigned int)s) << 16); }

DI f32x4 mfma16(s16x8 a, s16x8 b, f32x4 c) {
  return __builtin_amdgcn_mfma_f32_16x16x32_bf16(a, b, c, 0, 0, 0);
}

// ---------------- kw: one-shot weight conversion ----------------
__global__ __launch_bounds__(256) void kw_conv(
    const float* __restrict__ wq, const float* __restrict__ wk,
    const float* __restrict__ wv, const float* __restrict__ wp,
    unsigned short* __restrict__ WQ, unsigned short* __restrict__ WK,
    unsigned short* __restrict__ WV, unsigned short* __restrict__ WPH,
    unsigned short* __restrict__ WPL) {
  int idx = (blockIdx.x * 256 + threadIdx.x) * 4;  // over 65536 elems
  f32x4 q = *(const f32x4*)(wq + idx);
  f32x4 k = *(const f32x4*)(wk + idx);
  f32x4 v = *(const f32x4*)(wv + idx);
  f32x4 p = *(const f32x4*)(wp + idx);
  u16x4 oq, ok, ov, oh, ol;
#pragma unroll
  for (int e = 0; e < 4; ++e) {
    oq[e] = f2bf(q[e] * 0.0625f);
    ok[e] = f2bf(k[e]);
    ov[e] = f2bf(v[e]);
    unsigned short h = f2bf(p[e]);
    oh[e] = h;
    ol[e] = f2bf(p[e] - bf2f(h));
  }
  *(u16x4*)(WQ + idx) = oq;
  *(u16x4*)(WK + idx) = ok;
  *(u16x4*)(WV + idx) = ov;
  *(u16x4*)(WPH + idx) = oh;
  *(u16x4*)(WPL + idx) = ol;
}

// ---------------- k0: transpose X [b,c,n] f32 -> XT [b,n,c] bf16 ----------------
__global__ __launch_bounds__(256) void k0_transpose(const float* __restrict__ X,
                                                    unsigned short* __restrict__ XT) {
  __shared__ float tile[64 * 65];
  int t = threadIdx.x;
  int wg = blockIdx.x;
  int b = wg >> 8, rem = wg & 255;
  int c0 = (rem >> 6) * 64, n0 = (rem & 63) * 64;
  const float* xb = X + (size_t)b * C * N;
  int cl = t >> 2, ng = (t & 3) * 16;
#pragma unroll
  for (int k = 0; k < 4; ++k) {
    f32x4 v = *(const f32x4*)(xb + (size_t)(c0 + cl) * N + n0 + ng + k * 4);
#pragma unroll
    for (int e = 0; e < 4; ++e) tile[cl * 65 + ng + k * 4 + e] = v[e];
  }
  __syncthreads();
  int nl = t >> 2, cg = (t & 3) * 16;
  unsigned short* xtb = XT + (size_t)b * N * C;
  s16x8 o0v, o1v;
#pragma unroll
  for (int j = 0; j < 8; ++j) o0v[j] = (short)f2bf(tile[(cg + j) * 65 + nl]);
#pragma unroll
  for (int j = 0; j < 8; ++j) o1v[j] = (short)f2bf(tile[(cg + 8 + j) * 65 + nl]);
  *(s16x8*)(xtb + (size_t)(n0 + nl) * C + c0 + cg) = o0v;
  *(s16x8*)(xtb + (size_t)(n0 + nl) * C + c0 + cg + 8) = o1v;
}

// ---------------- k1: QKV projections (bf16 weights) ----------------
__global__ __launch_bounds__(256) void k1_qkv(
    const unsigned short* __restrict__ XT,
    const unsigned short* __restrict__ WQ, const float* __restrict__ bq,
    const unsigned short* __restrict__ WK, const float* __restrict__ bk,
    const unsigned short* __restrict__ WV, const float* __restrict__ bv,
    unsigned short* __restrict__ QT, unsigned short* __restrict__ KT,
    unsigned short* __restrict__ V) {
  int t = threadIdx.x, lane = t & 63, w = t >> 6, l15 = lane & 15, g = lane >> 4;
  int wg = blockIdx.x, b = wg >> 6, nb = wg & 63;
  int n0 = nb * 64;
  const unsigned short* xtb = XT + (size_t)b * N * C;
  const unsigned short* Ws[3] = {WQ, WK, WV};
  const float* Bs[3] = {bq, bk, bv};
#pragma unroll
  for (int np = 0; np < 2; ++np) {
    s16x8 xf[2][8];
#pragma unroll
    for (int n2 = 0; n2 < 2; ++n2)
#pragma unroll
      for (int cc = 0; cc < 8; ++cc)
        xf[n2][cc] = *(const s16x8*)(xtb + (size_t)(n0 + np * 32 + n2 * 16 + l15) * C + cc * 32 + g * 8);
#pragma unroll
    for (int ty = 0; ty < 3; ++ty) {
      float bsc = (ty == 0) ? 0.0625f : 1.0f;
#pragma unroll
      for (int ot = 0; ot < 4; ++ot) {
        int o0 = w * 64 + ot * 16;
        f32x4 bias = *(const f32x4*)(Bs[ty] + o0 + g * 4);
        s16x8 wf[8];
#pragma unroll
        for (int cc = 0; cc < 8; ++cc)
          wf[cc] = *(const s16x8*)(Ws[ty] + (size_t)(o0 + l15) * C + cc * 32 + g * 8);
#pragma unroll
        for (int n2 = 0; n2 < 2; ++n2) {
          f32x4 D = {0.f, 0.f, 0.f, 0.f};
#pragma unroll
          for (int cc = 0; cc < 8; ++cc) D = mfma16(wf[cc], xf[n2][cc], D);
          int n = n0 + np * 32 + n2 * 16 + l15;
          if (ty < 2) {
            s16x4 pk;
#pragma unroll
            for (int r = 0; r < 4; ++r) pk[r] = (short)f2bf(D[r] + bias[r] * bsc);
            unsigned short* dst = (ty == 0 ? QT : KT) + (size_t)b * N * C + (size_t)n * C + o0 + g * 4;
            *(s16x4*)dst = pk;
          } else {
#pragma unroll
            for (int r = 0; r < 4; ++r)
              V[(size_t)b * C * N + (size_t)(o0 + g * 4 + r) * N + n] = f2bf(D[r] + bias[r]);
          }
        }
      }
    }
  }
}

// ---------------- k2: Lp[isplit][b][j] = partial sum_i exp(S[i,j]-12) ----------------
// grid 1024: isplit = wg&3, jb = (wg>>2)&63, b = wg>>8. Wave w owns 16 j. Plain stores.
__global__ __launch_bounds__(256, 4) void k2_stats(
    const unsigned short* __restrict__ QT, const unsigned short* __restrict__ KT,
    float* __restrict__ Lp) {
  int t = threadIdx.x, lane = t & 63, w = t >> 6, l15 = lane & 15, g = lane >> 4;
  int wg = blockIdx.x, isplit = wg & 3, jb = (wg >> 2) & 63, b = wg >> 8;
  const unsigned short* qtb = QT + (size_t)b * N * C;
  const unsigned short* ktb = KT + (size_t)b * N * C;
  s16x8 kf[8];
#pragma unroll
  for (int cc = 0; cc < 8; ++cc)
    kf[cc] = *(const s16x8*)(ktb + (size_t)(jb * 64 + w * 16 + l15) * C + cc * 32 + g * 8);
  float sums[4] = {0.f, 0.f, 0.f, 0.f};
  for (int ii = 0; ii < 16; ++ii) {
    int i0 = isplit * 1024 + ii * 64;
    f32x4 D[4];
#pragma unroll
    for (int it = 0; it < 4; ++it) D[it] = (f32x4){0.f, 0.f, 0.f, 0.f};
#pragma unroll
    for (int it = 0; it < 4; ++it)
#pragma unroll
      for (int cc = 0; cc < 8; ++cc) {
        s16x8 qf = *(const s16x8*)(qtb + (size_t)(i0 + it * 16 + l15) * C + cc * 32 + g * 8);
        D[it] = mfma16(kf[cc], qf, D[it]);
      }
#pragma unroll
    for (int it = 0; it < 4; ++it)
#pragma unroll
      for (int r = 0; r < 4; ++r) sums[r] += __expf(D[it][r] - 12.f);
  }
#pragma unroll
  for (int off = 1; off < 16; off <<= 1)
#pragma unroll
    for (int r = 0; r < 4; ++r) sums[r] += __shfl_xor(sums[r], off);
  if (l15 == 0) {
    f32x4 o = {sums[0], sums[1], sums[2], sums[3]};
    *(f32x4*)&Lp[(size_t)(isplit * 4 + b) * N + jb * 64 + w * 16 + g * 4] = o;
  }
}

// ---------------- k2b: V[c,j] /= sum_s Lp[s][b][j] ----------------
__global__ __launch_bounds__(256) void k2b_scale_v(unsigned short* __restrict__ V,
                                                   const float* __restrict__ Lp) {
  int idx4 = (blockIdx.x * 256 + threadIdx.x) * 4;  // over B*C*N
  int b = idx4 >> 20, n4 = idx4 & (N - 1);
  u16x4 v = *(u16x4*)(V + (size_t)idx4);
  f32x4 lv = *(const f32x4*)(Lp + (size_t)b * N + n4);
#pragma unroll
  for (int s = 1; s < 4; ++s) {
    f32x4 l2 = *(const f32x4*)(Lp + (size_t)(s * 4 + b) * N + n4);
#pragma unroll
    for (int e = 0; e < 4; ++e) lv[e] += l2[e];
  }
  u16x4 o;
#pragma unroll
  for (int e = 0; e < 4; ++e) o[e] = f2bf(bf2f(v[e]) / lv[e]);
  *(u16x4*)(V + (size_t)idx4) = o;
}

// ---------------- k3: attention core, NO atomics ----------------
// grid 1024: ib = wg&255 (16-i tile), b = wg>>8. Block sweeps ALL 4096 j in 64 phases.
// Per phase (64 j): wave w computes S for j-tile w (16 j) x the block's 16 i;
// P into double-buffered LDS; one barrier; PV: wave w owns c-range w*64.
__global__ __launch_bounds__(256, 4) void k3_attn(
    const unsigned short* __restrict__ QT, const unsigned short* __restrict__ KT,
    const unsigned short* __restrict__ V, float* __restrict__ OT) {
  __shared__ short pl[2][16 * 66];  // P [16 i][64 j], row stride 66 shorts, dbuf
  int t = threadIdx.x, lane = t & 63, w = t >> 6, l15 = lane & 15, g = lane >> 4;
  int wg = blockIdx.x, ib = wg & 255, b = wg >> 8;
  const unsigned short* qtb = QT + (size_t)b * N * C;
  const unsigned short* ktb = KT + (size_t)b * N * C;
  const unsigned short* vb = V + (size_t)b * C * N;
  float* otb = OT + (size_t)b * N * C;
  s16x8 qf[8];
#pragma unroll
  for (int cc = 0; cc < 8; ++cc)
    qf[cc] = *(const s16x8*)(qtb + (size_t)(ib * 16 + l15) * C + cc * 32 + g * 8);
  f32x4 acc[4];
#pragma unroll
  for (int ct = 0; ct < 4; ++ct) acc[ct] = (f32x4){0.f, 0.f, 0.f, 0.f};

  for (int ph = 0; ph < 64; ++ph) {
    int J0 = ph * 64;
    int jrow = J0 + w * 16 + l15;
    // QK: wave's 16-j tile x block's 16 i; 2 independent cc-chains
    f32x4 Da = {0.f, 0.f, 0.f, 0.f}, Db = {0.f, 0.f, 0.f, 0.f};
#pragma unroll
    for (int cc = 0; cc < 4; ++cc) {
      s16x8 ka = *(const s16x8*)(ktb + (size_t)jrow * C + cc * 32 + g * 8);
      s16x8 kb = *(const s16x8*)(ktb + (size_t)jrow * C + (cc + 4) * 32 + g * 8);
      Da = mfma16(ka, qf[cc], Da);
      Db = mfma16(kb, qf[cc + 4], Db);
    }
    s16x4 p;
#pragma unroll
    for (int r = 0; r < 4; ++r) p[r] = (short)f2bf(__expf(Da[r] + Db[r] - 12.f));
    // P[i=l15][j = w*16 + 4g + r]
    *(s16x4*)&pl[ph & 1][l15 * 66 + w * 16 + g * 4] = p;
    __syncthreads();
    // PV: wave w owns c-range w*64 (4 ct tiles); k over 64 j in 2 chunks
#pragma unroll
    for (int kc = 0; kc < 2; ++kc) {
      s16x8 pf = *(const s16x8*)&pl[ph & 1][l15 * 66 + kc * 32 + g * 8];
#pragma unroll
      for (int ct = 0; ct < 4; ++ct) {
        s16x8 vf = *(const s16x8*)(vb + (size_t)(w * 64 + ct * 16 + l15) * N + J0 + kc * 32 + g * 8);
        acc[ct] = mfma16(vf, pf, acc[ct]);
      }
    }
  }
  // D: col = l15 = i, row = 4g+r = c-within-tile -> contiguous f32x4 store
#pragma unroll
  for (int ct = 0; ct < 4; ++ct)
    *(f32x4*)&otb[(size_t)(ib * 16 + l15) * C + w * 64 + ct * 16 + g * 4] = acc[ct];
}

// ---------------- k4: proj with split-bf16 (hi/lo), pre-split weights ----------------
__global__ __launch_bounds__(256) void k4_proj(const float* __restrict__ OT,
                                               const unsigned short* __restrict__ WPH,
                                               const unsigned short* __restrict__ WPL,
                                               const float* __restrict__ bp,
                                               float* __restrict__ OUT) {
  int t = threadIdx.x, lane = t & 63, w = t >> 6, l15 = lane & 15, g = lane >> 4;
  int wg = blockIdx.x, b = wg >> 6, nb = wg & 63;
  const float* otb = OT + (size_t)b * N * C;
  float* ob = OUT + (size_t)b * (size_t)C * N;
  for (int nt = 0; nt < 4; ++nt) {
    s16x8 xh[8], xl[8];
#pragma unroll
    for (int cc = 0; cc < 8; ++cc) {
      const float* p = otb + (size_t)(nb * 64 + nt * 16 + l15) * C + cc * 32 + g * 8;
      f32x4 a = *(const f32x4*)p;
      f32x4 b2 = *(const f32x4*)(p + 4);
      s16x8 h, lo;
#pragma unroll
      for (int e = 0; e < 4; ++e) {
        unsigned short hh = f2bf(a[e]); h[e] = (short)hh; lo[e] = (short)f2bf(a[e] - bf2f(hh));
        unsigned short h2 = f2bf(b2[e]); h[e + 4] = (short)h2; lo[e + 4] = (short)f2bf(b2[e] - bf2f(h2));
      }
      xh[cc] = h; xl[cc] = lo;
    }
#pragma unroll
    for (int ot = 0; ot < 4; ++ot) {
      int o0 = w * 64 + ot * 16;
      f32x4 bias = *(const f32x4*)(bp + o0 + g * 4);
      f32x4 D = {0.f, 0.f, 0.f, 0.f};
#pragma unroll
      for (int cc = 0; cc < 8; ++cc) {
        s16x8 h = *(const s16x8*)(WPH + (size_t)(o0 + l15) * C + cc * 32 + g * 8);
        s16x8 lo = *(const s16x8*)(WPL + (size_t)(o0 + l15) * C + cc * 32 + g * 8);
        D = mfma16(h, xh[cc], D);
        D = mfma16(h, xl[cc], D);
        D = mfma16(lo, xh[cc], D);
      }
#pragma unroll
      for (int r = 0; r < 4; ++r)
        ob[(size_t)(o0 + g * 4 + r) * N + nb * 64 + nt * 16 + l15] = D[r] + bias[r];
    }
  }
}

extern "C" void kernel_launch(void* const* d_in, const int* in_sizes, int n_in,
                              void* d_out, int out_size, void* d_ws, size_t ws_size,
                              hipStream_t stream) {
  const float* x = (const float*)d_in[0];
  const float* wq = (const float*)d_in[1];
  const float* bq = (const float*)d_in[2];
  const float* wk = (const float*)d_in[3];
  const float* bk = (const float*)d_in[4];
  const float* wv = (const float*)d_in[5];
  const float* bv = (const float*)d_in[6];
  const float* wp = (const float*)d_in[7];
  const float* bp = (const float*)d_in[8];
  float* out = (float*)d_out;
  char* ws = (char*)d_ws;
  // workspace layout (43 MB total; XT/OT overlap — XT dead after k1):
  unsigned short* QT = (unsigned short*)(ws + 0);          //  8 MB bf16 [B][N][C] (pre-scaled /16)
  unsigned short* KT = (unsigned short*)(ws + 8388608);    //  8 MB bf16 [B][N][C]
  unsigned short* V  = (unsigned short*)(ws + 16777216);   //  8 MB bf16 [B][C][N]
  unsigned short* WQ = (unsigned short*)(ws + 25165824);   // 128 KB each
  unsigned short* WK = (unsigned short*)(ws + 25296896);
  unsigned short* WV = (unsigned short*)(ws + 25427968);
  unsigned short* WPH = (unsigned short*)(ws + 25559040);
  unsigned short* WPL = (unsigned short*)(ws + 25690112);
  float* Lp = (float*)(ws + 25821184);                     // 256 KB f32 [4][B][N]
  unsigned short* XT = (unsigned short*)(ws + 26214400);   //  8 MB bf16 (k0..k1 only)
  float* OT = (float*)(ws + 26214400);                     // 16 MB f32 (after k1)

  hipLaunchKernelGGL(kw_conv, dim3(64), dim3(256), 0, stream, wq, wk, wv, wp, WQ, WK, WV, WPH, WPL);
  hipLaunchKernelGGL(k0_transpose, dim3(1024), dim3(256), 0, stream, x, XT);
  hipLaunchKernelGGL(k1_qkv, dim3(256), dim3(256), 0, stream, XT, WQ, bq, WK, bk, WV, bv, QT, KT, V);
  hipLaunchKernelGGL(k2_stats, dim3(1024), dim3(256), 0, stream, QT, KT, Lp);
  hipLaunchKernelGGL(k2b_scale_v, dim3(4096), dim3(256), 0, stream, V, Lp);
  hipLaunchKernelGGL(k3_attn, dim3(1024), dim3(256), 0, stream, QT, KT, V, OT);
  hipLaunchKernelGGL(k4_proj, dim3(256), dim3(256), 0, stream, OT, WPH, WPL, bp, out);
}

// Round 5
// 438.786 us; speedup vs baseline: 1.8941x; 1.8941x over previous
//
#include <hip/hip_runtime.h>
#include <stdint.h>

// Attention_45148696216940: B=4, C=256, H=W=64 -> N=4096
// softmax over axis=1 (i) = column softmax of S[i,j].
// Pipeline (bf16 MFMA 16x16x32, fp32 accum), no global atomics:
//   kw: weight conversion (WQ/16, WK, WV, WPh/WPl hi-lo split)
//   k0: X[b,c,n] f32 -> XT[b,n,c] bf16
//   k1: QT, KT [b,n,c], V [b,c,n] (bf16)
//   k2: Lp[s][b][j] = partial sum_i exp(S[i,j]-12)  (4 i-slices, plain stores)
//   k2b: V[c,j] /= sum_s Lp[s][b][j]
//   k3: flash-style: block owns (b, 64 i), sweeps all j in 128 phases of 32;
//       K/V tiles LDS-staged (dbuf), P in LDS, direct OT stores.
//       XCD-aware block mapping: wg%8 -> (batch, i-half) so each XCD's L2
//       holds one batch's K+V (4 MB).
//   k4: out = Wp . O + bp with split-bf16 (hi/lo)
//
// MFMA conventions: A row m = lane&15, B col n = lane&15, k = 32*cc + 8*(lane>>4) + e
// C/D: col = lane&15, row = 4*(lane>>4) + reg

#define DI __device__ __forceinline__
typedef __attribute__((ext_vector_type(4))) float f32x4;
typedef __attribute__((ext_vector_type(8))) short s16x8;
typedef __attribute__((ext_vector_type(4))) short s16x4;
typedef __attribute__((ext_vector_type(4))) unsigned short u16x4;

constexpr int C = 256;
constexpr int N = 4096;

DI unsigned short f2bf(float f) {
  unsigned int u = __float_as_uint(f);
  u += 0x7FFFu + ((u >> 16) & 1u);   // RNE
  return (unsigned short)(u >> 16);
}
DI float bf2f(unsigned short s) { return __uint_as_float(((unsigned int)s) << 16); }

DI f32x4 mfma16(s16x8 a, s16x8 b, f32x4 c) {
  return __builtin_amdgcn_mfma_f32_16x16x32_bf16(a, b, c, 0, 0, 0);
}

// ---------------- kw: one-shot weight conversion ----------------
__global__ __launch_bounds__(256) void kw_conv(
    const float* __restrict__ wq, const float* __restrict__ wk,
    const float* __restrict__ wv, const float* __restrict__ wp,
    unsigned short* __restrict__ WQ, unsigned short* __restrict__ WK,
    unsigned short* __restrict__ WV, unsigned short* __restrict__ WPH,
    unsigned short* __restrict__ WPL) {
  int idx = (blockIdx.x * 256 + threadIdx.x) * 4;
  f32x4 q = *(const f32x4*)(wq + idx);
  f32x4 k = *(const f32x4*)(wk + idx);
  f32x4 v = *(const f32x4*)(wv + idx);
  f32x4 p = *(const f32x4*)(wp + idx);
  u16x4 oq, ok, ov, oh, ol;
#pragma unroll
  for (int e = 0; e < 4; ++e) {
    oq[e] = f2bf(q[e] * 0.0625f);
    ok[e] = f2bf(k[e]);
    ov[e] = f2bf(v[e]);
    unsigned short h = f2bf(p[e]);
    oh[e] = h;
    ol[e] = f2bf(p[e] - bf2f(h));
  }
  *(u16x4*)(WQ + idx) = oq;
  *(u16x4*)(WK + idx) = ok;
  *(u16x4*)(WV + idx) = ov;
  *(u16x4*)(WPH + idx) = oh;
  *(u16x4*)(WPL + idx) = ol;
}

// ---------------- k0: transpose X [b,c,n] f32 -> XT [b,n,c] bf16 ----------------
__global__ __launch_bounds__(256) void k0_transpose(const float* __restrict__ X,
                                                    unsigned short* __restrict__ XT) {
  __shared__ float tile[64 * 65];
  int t = threadIdx.x;
  int wg = blockIdx.x;
  int b = wg >> 8, rem = wg & 255;
  int c0 = (rem >> 6) * 64, n0 = (rem & 63) * 64;
  const float* xb = X + (size_t)b * C * N;
  int cl = t >> 2, ng = (t & 3) * 16;
#pragma unroll
  for (int k = 0; k < 4; ++k) {
    f32x4 v = *(const f32x4*)(xb + (size_t)(c0 + cl) * N + n0 + ng + k * 4);
#pragma unroll
    for (int e = 0; e < 4; ++e) tile[cl * 65 + ng + k * 4 + e] = v[e];
  }
  __syncthreads();
  int nl = t >> 2, cg = (t & 3) * 16;
  unsigned short* xtb = XT + (size_t)b * N * C;
  s16x8 o0v, o1v;
#pragma unroll
  for (int j = 0; j < 8; ++j) o0v[j] = (short)f2bf(tile[(cg + j) * 65 + nl]);
#pragma unroll
  for (int j = 0; j < 8; ++j) o1v[j] = (short)f2bf(tile[(cg + 8 + j) * 65 + nl]);
  *(s16x8*)(xtb + (size_t)(n0 + nl) * C + c0 + cg) = o0v;
  *(s16x8*)(xtb + (size_t)(n0 + nl) * C + c0 + cg + 8) = o1v;
}

// ---------------- k1: QKV projections (bf16 weights) ----------------
__global__ __launch_bounds__(256) void k1_qkv(
    const unsigned short* __restrict__ XT,
    const unsigned short* __restrict__ WQ, const float* __restrict__ bq,
    const unsigned short* __restrict__ WK, const float* __restrict__ bk,
    const unsigned short* __restrict__ WV, const float* __restrict__ bv,
    unsigned short* __restrict__ QT, unsigned short* __restrict__ KT,
    unsigned short* __restrict__ V) {
  int t = threadIdx.x, lane = t & 63, w = t >> 6, l15 = lane & 15, g = lane >> 4;
  int wg = blockIdx.x, b = wg >> 6, nb = wg & 63;
  int n0 = nb * 64;
  const unsigned short* xtb = XT + (size_t)b * N * C;
  const unsigned short* Ws[3] = {WQ, WK, WV};
  const float* Bs[3] = {bq, bk, bv};
#pragma unroll
  for (int np = 0; np < 2; ++np) {
    s16x8 xf[2][8];
#pragma unroll
    for (int n2 = 0; n2 < 2; ++n2)
#pragma unroll
      for (int cc = 0; cc < 8; ++cc)
        xf[n2][cc] = *(const s16x8*)(xtb + (size_t)(n0 + np * 32 + n2 * 16 + l15) * C + cc * 32 + g * 8);
#pragma unroll
    for (int ty = 0; ty < 3; ++ty) {
      float bsc = (ty == 0) ? 0.0625f : 1.0f;
#pragma unroll
      for (int ot = 0; ot < 4; ++ot) {
        int o0 = w * 64 + ot * 16;
        f32x4 bias = *(const f32x4*)(Bs[ty] + o0 + g * 4);
        s16x8 wf[8];
#pragma unroll
        for (int cc = 0; cc < 8; ++cc)
          wf[cc] = *(const s16x8*)(Ws[ty] + (size_t)(o0 + l15) * C + cc * 32 + g * 8);
#pragma unroll
        for (int n2 = 0; n2 < 2; ++n2) {
          f32x4 D = {0.f, 0.f, 0.f, 0.f};
#pragma unroll
          for (int cc = 0; cc < 8; ++cc) D = mfma16(wf[cc], xf[n2][cc], D);
          int n = n0 + np * 32 + n2 * 16 + l15;
          if (ty < 2) {
            s16x4 pk;
#pragma unroll
            for (int r = 0; r < 4; ++r) pk[r] = (short)f2bf(D[r] + bias[r] * bsc);
            unsigned short* dst = (ty == 0 ? QT : KT) + (size_t)b * N * C + (size_t)n * C + o0 + g * 4;
            *(s16x4*)dst = pk;
          } else {
#pragma unroll
            for (int r = 0; r < 4; ++r)
              V[(size_t)b * C * N + (size_t)(o0 + g * 4 + r) * N + n] = f2bf(D[r] + bias[r]);
          }
        }
      }
    }
  }
}

// ---------------- k2: Lp[s][b][j] = partial sum_i exp(S[i,j]-12) ----------------
// grid 512: jb = wg&31 (128 j), isplit = (wg>>5)&3 (1024 i), b = wg>>7.
// Wave w owns j-range w*32 (2 j-tiles); K frags live in registers.
__global__ __launch_bounds__(256, 2) void k2_stats(
    const unsigned short* __restrict__ QT, const unsigned short* __restrict__ KT,
    float* __restrict__ Lp) {
  int t = threadIdx.x, lane = t & 63, w = t >> 6, l15 = lane & 15, g = lane >> 4;
  int wg = blockIdx.x, jb = wg & 31, isplit = (wg >> 5) & 3, b = wg >> 7;
  const unsigned short* qtb = QT + (size_t)b * N * C;
  const unsigned short* ktb = KT + (size_t)b * N * C;
  s16x8 kf[2][8];
#pragma unroll
  for (int jt = 0; jt < 2; ++jt)
#pragma unroll
    for (int cc = 0; cc < 8; ++cc)
      kf[jt][cc] = *(const s16x8*)(ktb + (size_t)(jb * 128 + w * 32 + jt * 16 + l15) * C + cc * 32 + g * 8);
  float sums[2][4];
#pragma unroll
  for (int jt = 0; jt < 2; ++jt)
#pragma unroll
    for (int r = 0; r < 4; ++r) sums[jt][r] = 0.f;
  for (int it = 0; it < 64; ++it) {
    int i0 = isplit * 1024 + it * 16;
    f32x4 D0 = {0.f, 0.f, 0.f, 0.f}, D1 = {0.f, 0.f, 0.f, 0.f};
#pragma unroll
    for (int cc = 0; cc < 8; ++cc) {
      s16x8 qf = *(const s16x8*)(qtb + (size_t)(i0 + l15) * C + cc * 32 + g * 8);
      D0 = mfma16(kf[0][cc], qf, D0);
      D1 = mfma16(kf[1][cc], qf, D1);
    }
#pragma unroll
    for (int r = 0; r < 4; ++r) {
      sums[0][r] += __expf(D0[r] - 12.f);
      sums[1][r] += __expf(D1[r] - 12.f);
    }
  }
#pragma unroll
  for (int off = 1; off < 16; off <<= 1)
#pragma unroll
    for (int jt = 0; jt < 2; ++jt)
#pragma unroll
      for (int r = 0; r < 4; ++r) sums[jt][r] += __shfl_xor(sums[jt][r], off);
  if (l15 == 0) {
#pragma unroll
    for (int jt = 0; jt < 2; ++jt) {
      f32x4 o = {sums[jt][0], sums[jt][1], sums[jt][2], sums[jt][3]};
      *(f32x4*)&Lp[(size_t)(isplit * 4 + b) * N + jb * 128 + w * 32 + jt * 16 + g * 4] = o;
    }
  }
}

// ---------------- k2b: V[c,j] /= sum_s Lp[s][b][j] ----------------
__global__ __launch_bounds__(256) void k2b_scale_v(unsigned short* __restrict__ V,
                                                   const float* __restrict__ Lp) {
  int idx4 = (blockIdx.x * 256 + threadIdx.x) * 4;  // over B*C*N
  int b = idx4 >> 20, n4 = idx4 & (N - 1);
  u16x4 v = *(u16x4*)(V + (size_t)idx4);
  f32x4 lv = *(const f32x4*)(Lp + (size_t)b * N + n4);
#pragma unroll
  for (int s = 1; s < 4; ++s) {
    f32x4 l2 = *(const f32x4*)(Lp + (size_t)(s * 4 + b) * N + n4);
#pragma unroll
    for (int e = 0; e < 4; ++e) lv[e] += l2[e];
  }
  u16x4 o;
#pragma unroll
  for (int e = 0; e < 4; ++e) o[e] = f2bf(bf2f(v[e]) / lv[e]);
  *(u16x4*)(V + (size_t)idx4) = o;
}

// ---------------- k3: flash attention core ----------------
// grid 256: x = wg&7 -> XCD slot: b = x>>1, ihalf = x&1; ib = ihalf*32 + (wg>>3).
// Block owns 64 i rows; sweeps 4096 j in 128 phases of 32.
// Wave w: QK for i-tiles {2*(w>>1), 2*(w>>1)+1} x j-tile (w&1); PV for c-range w*64.
// LDS strides (shorts): K 264, V 40, P 40 (16B-aligned rows, <=2-way bank alias on reads).
__global__ __launch_bounds__(256, 2) void k3_attn(
    const unsigned short* __restrict__ QT, const unsigned short* __restrict__ KT,
    const unsigned short* __restrict__ V, float* __restrict__ OT) {
  __shared__ short K_lds[2][32 * 264];   // [buf][32 j][256 c +8]
  __shared__ short V_lds[2][256 * 40];   // [buf][256 c][32 j +8]
  __shared__ short P_lds[64 * 40];       // [64 i][32 j +8]
  int t = threadIdx.x, lane = t & 63, w = t >> 6, l15 = lane & 15, g = lane >> 4;
  int wg = blockIdx.x;
  int x = wg & 7, b = x >> 1, ib = (x & 1) * 32 + (wg >> 3);
  int jt = w & 1, ip = w >> 1;
  const unsigned short* qtb = QT + (size_t)b * N * C;
  const unsigned short* ktb = KT + (size_t)b * N * C;
  const unsigned short* vb = V + (size_t)b * C * N;
  float* otb = OT + (size_t)b * N * C;
  // staging geometry: K: thread t -> row t>>3, seg (t&7)*32 shorts; V: row t, 32 j.
  int krow = t >> 3, kcol = (t & 7) * 32;

  // Q fragments for this wave's two i-tiles (held in registers all kernel)
  s16x8 qf[2][8];
#pragma unroll
  for (int tt = 0; tt < 2; ++tt)
#pragma unroll
    for (int cc = 0; cc < 8; ++cc)
      qf[tt][cc] = *(const s16x8*)(qtb + (size_t)(ib * 64 + (ip * 2 + tt) * 16 + l15) * C + cc * 32 + g * 8);

  f32x4 acc[4][4];  // [ct][it]
#pragma unroll
  for (int ct = 0; ct < 4; ++ct)
#pragma unroll
    for (int it = 0; it < 4; ++it) acc[ct][it] = (f32x4){0.f, 0.f, 0.f, 0.f};

  // prologue: stage phase 0 into buf 0
  {
    const unsigned short* kg = ktb + (size_t)krow * C + kcol;
    const unsigned short* vg = vb + (size_t)t * N;
#pragma unroll
    for (int k = 0; k < 4; ++k) {
      f32x4 kv = *(const f32x4*)(kg + k * 8);
      f32x4 vv = *(const f32x4*)(vg + k * 8);
      *(f32x4*)&K_lds[0][krow * 264 + kcol + k * 8] = kv;
      *(f32x4*)&V_lds[0][t * 40 + k * 8] = vv;
    }
  }
  __syncthreads();

  for (int ph = 0; ph < 128; ++ph) {
    int cur = ph & 1;
    // prefetch next K/V tile into registers (lands during this phase's compute)
    f32x4 kreg[4], vreg[4];
    if (ph < 127) {
      int J1 = (ph + 1) * 32;
      const unsigned short* kg = ktb + (size_t)(J1 + krow) * C + kcol;
      const unsigned short* vg = vb + (size_t)t * N + J1;
#pragma unroll
      for (int k = 0; k < 4; ++k) {
        kreg[k] = *(const f32x4*)(kg + k * 8);
        vreg[k] = *(const f32x4*)(vg + k * 8);
      }
    }
    // QK: K frags from LDS (shared across both i-tiles)
    s16x8 kf[8];
#pragma unroll
    for (int cc = 0; cc < 8; ++cc)
      kf[cc] = *(const s16x8*)&K_lds[cur][(jt * 16 + l15) * 264 + cc * 32 + g * 8];
    f32x4 D0 = {0.f, 0.f, 0.f, 0.f}, D1 = {0.f, 0.f, 0.f, 0.f};
#pragma unroll
    for (int cc = 0; cc < 8; ++cc) {
      D0 = mfma16(kf[cc], qf[0][cc], D0);
      D1 = mfma16(kf[cc], qf[1][cc], D1);
    }
    // P = exp(S-12): D col(l15)=i-within-tile, row(4g+r)=j-within-tile
    s16x4 p0, p1;
#pragma unroll
    for (int r = 0; r < 4; ++r) {
      p0[r] = (short)f2bf(__expf(D0[r] - 12.f));
      p1[r] = (short)f2bf(__expf(D1[r] - 12.f));
    }
    *(s16x4*)&P_lds[((ip * 2 + 0) * 16 + l15) * 40 + jt * 16 + g * 4] = p0;
    *(s16x4*)&P_lds[((ip * 2 + 1) * 16 + l15) * 40 + jt * 16 + g * 4] = p1;
    __syncthreads();
    // PV: wave w owns c-range w*64
    s16x8 pf[4];
#pragma unroll
    for (int it = 0; it < 4; ++it)
      pf[it] = *(const s16x8*)&P_lds[(it * 16 + l15) * 40 + g * 8];
#pragma unroll
    for (int ct = 0; ct < 4; ++ct) {
      s16x8 vf = *(const s16x8*)&V_lds[cur][(w * 64 + ct * 16 + l15) * 40 + g * 8];
#pragma unroll
      for (int it = 0; it < 4; ++it) acc[ct][it] = mfma16(vf, pf[it], acc[ct][it]);
    }
    // write prefetched tile to the other buffer
    if (ph < 127) {
      int nxt = cur ^ 1;
#pragma unroll
      for (int k = 0; k < 4; ++k) {
        *(f32x4*)&K_lds[nxt][krow * 264 + kcol + k * 8] = kreg[k];
        *(f32x4*)&V_lds[nxt][t * 40 + k * 8] = vreg[k];
      }
    }
    __syncthreads();
  }
  // store: D col(l15) = i-within-tile, row(4g+r) = c-within-tile
#pragma unroll
  for (int ct = 0; ct < 4; ++ct)
#pragma unroll
    for (int it = 0; it < 4; ++it)
      *(f32x4*)&otb[(size_t)(ib * 64 + it * 16 + l15) * C + w * 64 + ct * 16 + g * 4] = acc[ct][it];
}

// ---------------- k4: proj with split-bf16 (hi/lo), pre-split weights ----------------
__global__ __launch_bounds__(256) void k4_proj(const float* __restrict__ OT,
                                               const unsigned short* __restrict__ WPH,
                                               const unsigned short* __restrict__ WPL,
                                               const float* __restrict__ bp,
                                               float* __restrict__ OUT) {
  int t = threadIdx.x, lane = t & 63, w = t >> 6, l15 = lane & 15, g = lane >> 4;
  int wg = blockIdx.x, b = wg >> 6, nb = wg & 63;
  const float* otb = OT + (size_t)b * N * C;
  float* ob = OUT + (size_t)b * (size_t)C * N;
  for (int nt = 0; nt < 4; ++nt) {
    s16x8 xh[8], xl[8];
#pragma unroll
    for (int cc = 0; cc < 8; ++cc) {
      const float* p = otb + (size_t)(nb * 64 + nt * 16 + l15) * C + cc * 32 + g * 8;
      f32x4 a = *(const f32x4*)p;
      f32x4 b2 = *(const f32x4*)(p + 4);
      s16x8 h, lo;
#pragma unroll
      for (int e = 0; e < 4; ++e) {
        unsigned short hh = f2bf(a[e]); h[e] = (short)hh; lo[e] = (short)f2bf(a[e] - bf2f(hh));
        unsigned short h2 = f2bf(b2[e]); h[e + 4] = (short)h2; lo[e + 4] = (short)f2bf(b2[e] - bf2f(h2));
      }
      xh[cc] = h; xl[cc] = lo;
    }
#pragma unroll
    for (int ot = 0; ot < 4; ++ot) {
      int o0 = w * 64 + ot * 16;
      f32x4 bias = *(const f32x4*)(bp + o0 + g * 4);
      f32x4 D = {0.f, 0.f, 0.f, 0.f};
#pragma unroll
      for (int cc = 0; cc < 8; ++cc) {
        s16x8 h = *(const s16x8*)(WPH + (size_t)(o0 + l15) * C + cc * 32 + g * 8);
        s16x8 lo = *(const s16x8*)(WPL + (size_t)(o0 + l15) * C + cc * 32 + g * 8);
        D = mfma16(h, xh[cc], D);
        D = mfma16(h, xl[cc], D);
        D = mfma16(lo, xh[cc], D);
      }
#pragma unroll
      for (int r = 0; r < 4; ++r)
        ob[(size_t)(o0 + g * 4 + r) * N + nb * 64 + nt * 16 + l15] = D[r] + bias[r];
    }
  }
}

extern "C" void kernel_launch(void* const* d_in, const int* in_sizes, int n_in,
                              void* d_out, int out_size, void* d_ws, size_t ws_size,
                              hipStream_t stream) {
  const float* x = (const float*)d_in[0];
  const float* wq = (const float*)d_in[1];
  const float* bq = (const float*)d_in[2];
  const float* wk = (const float*)d_in[3];
  const float* bk = (const float*)d_in[4];
  const float* wv = (const float*)d_in[5];
  const float* bv = (const float*)d_in[6];
  const float* wp = (const float*)d_in[7];
  const float* bp = (const float*)d_in[8];
  float* out = (float*)d_out;
  char* ws = (char*)d_ws;
  // workspace layout (~42 MB; XT/OT overlap — XT dead after k1):
  unsigned short* QT = (unsigned short*)(ws + 0);          //  8 MB bf16 [B][N][C] (pre-scaled /16)
  unsigned short* KT = (unsigned short*)(ws + 8388608);    //  8 MB bf16 [B][N][C]
  unsigned short* V  = (unsigned short*)(ws + 16777216);   //  8 MB bf16 [B][C][N]
  unsigned short* WQ = (unsigned short*)(ws + 25165824);   // 128 KB each
  unsigned short* WK = (unsigned short*)(ws + 25296896);
  unsigned short* WV = (unsigned short*)(ws + 25427968);
  unsigned short* WPH = (unsigned short*)(ws + 25559040);
  unsigned short* WPL = (unsigned short*)(ws + 25690112);
  float* Lp = (float*)(ws + 25821184);                     // 256 KB f32 [4][B][N]
  unsigned short* XT = (unsigned short*)(ws + 26214400);   //  8 MB bf16 (k0..k1 only)
  float* OT = (float*)(ws + 26214400);                     // 16 MB f32 (after k1)

  hipLaunchKernelGGL(kw_conv, dim3(64), dim3(256), 0, stream, wq, wk, wv, wp, WQ, WK, WV, WPH, WPL);
  hipLaunchKernelGGL(k0_transpose, dim3(1024), dim3(256), 0, stream, x, XT);
  hipLaunchKernelGGL(k1_qkv, dim3(256), dim3(256), 0, stream, XT, WQ, bq, WK, bk, WV, bv, QT, KT, V);
  hipLaunchKernelGGL(k2_stats, dim3(512), dim3(256), 0, stream, QT, KT, Lp);
  hipLaunchKernelGGL(k2b_scale_v, dim3(4096), dim3(256), 0, stream, V, Lp);
  hipLaunchKernelGGL(k3_attn, dim3(256), dim3(256), 0, stream, QT, KT, V, OT);
  hipLaunchKernelGGL(k4_proj, dim3(256), dim3(256), 0, stream, OT, WPH, WPL, bp, out);
}

// Round 7
// 372.756 us; speedup vs baseline: 2.2296x; 1.1771x over previous
//
#include <hip/hip_runtime.h>
#include <stdint.h>

// Attention_45148696216940: B=4, C=256, H=W=64 -> N=4096
// softmax over axis=1 (i) = column softmax of S[i,j].
// Pipeline (bf16 MFMA, fp32 accum), no global atomics:
//   kw: weight conversion (WQ/16, WK, WV, WPh/WPl hi-lo split)
//   k0: X[b,c,n] f32 -> XT[b,n,c] bf16
//   k1: QT, KT [b,n,c], V [b,c,n] (bf16)
//   k2: Lp[s][b][j] = partial sum_i exp(S[i,j]-12)  (4 i-slices)
//   k2c: R[b][j] = 1 / sum_s Lp[s][b][j]
//   k3: 512-thr producer/consumer flash: waves 0-3 QK->P (32x32 MFMA, Q in regs),
//       waves 4-7 PV; P dbuf LDS; K/V single-buf with async-stage; P scaled by R.
//   k4: out = Wp . O + bp with split-bf16 (hi/lo)
//
// 16x16x32 fragments (k1,k2,k4): A row m = lane&15, k = 32*cc + 8*(lane>>4) + e;
//   C/D: col = lane&15, row = 4*(lane>>4) + reg.
// 32x32x16 fragments (k3): A row = lane&31, B col = lane&31, k = 8*(lane>>5)+e (self-consistent);
//   C/D (HW): col = lane&31, row = (reg&3) + 8*(reg>>2) + 4*(lane>>5).

#define DI __device__ __forceinline__
typedef __attribute__((ext_vector_type(4))) float f32x4;
typedef __attribute__((ext_vector_type(16))) float f32x16;
typedef __attribute__((ext_vector_type(8))) short s16x8;
typedef __attribute__((ext_vector_type(4))) short s16x4;
typedef __attribute__((ext_vector_type(4))) unsigned short u16x4;

constexpr int C = 256;
constexpr int N = 4096;

DI unsigned short f2bf(float f) {
  unsigned int u = __float_as_uint(f);
  u += 0x7FFFu + ((u >> 16) & 1u);   // RNE
  return (unsigned short)(u >> 16);
}
DI float bf2f(unsigned short s) { return __uint_as_float(((unsigned int)s) << 16); }

DI f32x4 mfma16(s16x8 a, s16x8 b, f32x4 c) {
  return __builtin_amdgcn_mfma_f32_16x16x32_bf16(a, b, c, 0, 0, 0);
}
DI f32x16 mfma32(s16x8 a, s16x8 b, f32x16 c) {
  return __builtin_amdgcn_mfma_f32_32x32x16_bf16(a, b, c, 0, 0, 0);
}
DI f32x16 zero16() {
  f32x16 z;
#pragma unroll
  for (int e = 0; e < 16; ++e) z[e] = 0.f;
  return z;
}

// ---------------- kw: one-shot weight conversion ----------------
__global__ __launch_bounds__(256) void kw_conv(
    const float* __restrict__ wq, const float* __restrict__ wk,
    const float* __restrict__ wv, const float* __restrict__ wp,
    unsigned short* __restrict__ WQ, unsigned short* __restrict__ WK,
    unsigned short* __restrict__ WV, unsigned short* __restrict__ WPH,
    unsigned short* __restrict__ WPL) {
  int idx = (blockIdx.x * 256 + threadIdx.x) * 4;
  f32x4 q = *(const f32x4*)(wq + idx);
  f32x4 k = *(const f32x4*)(wk + idx);
  f32x4 v = *(const f32x4*)(wv + idx);
  f32x4 p = *(const f32x4*)(wp + idx);
  u16x4 oq, ok, ov, oh, ol;
#pragma unroll
  for (int e = 0; e < 4; ++e) {
    oq[e] = f2bf(q[e] * 0.0625f);
    ok[e] = f2bf(k[e]);
    ov[e] = f2bf(v[e]);
    unsigned short h = f2bf(p[e]);
    oh[e] = h;
    ol[e] = f2bf(p[e] - bf2f(h));
  }
  *(u16x4*)(WQ + idx) = oq;
  *(u16x4*)(WK + idx) = ok;
  *(u16x4*)(WV + idx) = ov;
  *(u16x4*)(WPH + idx) = oh;
  *(u16x4*)(WPL + idx) = ol;
}

// ---------------- k0: transpose X [b,c,n] f32 -> XT [b,n,c] bf16 ----------------
__global__ __launch_bounds__(256) void k0_transpose(const float* __restrict__ X,
                                                    unsigned short* __restrict__ XT) {
  __shared__ float tile[64 * 65];
  int t = threadIdx.x;
  int wg = blockIdx.x;
  int b = wg >> 8, rem = wg & 255;
  int c0 = (rem >> 6) * 64, n0 = (rem & 63) * 64;
  const float* xb = X + (size_t)b * C * N;
  int cl = t >> 2, ng = (t & 3) * 16;
#pragma unroll
  for (int k = 0; k < 4; ++k) {
    f32x4 v = *(const f32x4*)(xb + (size_t)(c0 + cl) * N + n0 + ng + k * 4);
#pragma unroll
    for (int e = 0; e < 4; ++e) tile[cl * 65 + ng + k * 4 + e] = v[e];
  }
  __syncthreads();
  int nl = t >> 2, cg = (t & 3) * 16;
  unsigned short* xtb = XT + (size_t)b * N * C;
  s16x8 o0v, o1v;
#pragma unroll
  for (int j = 0; j < 8; ++j) o0v[j] = (short)f2bf(tile[(cg + j) * 65 + nl]);
#pragma unroll
  for (int j = 0; j < 8; ++j) o1v[j] = (short)f2bf(tile[(cg + 8 + j) * 65 + nl]);
  *(s16x8*)(xtb + (size_t)(n0 + nl) * C + c0 + cg) = o0v;
  *(s16x8*)(xtb + (size_t)(n0 + nl) * C + c0 + cg + 8) = o1v;
}

// ---------------- k1: QKV projections (bf16 weights) ----------------
__global__ __launch_bounds__(256) void k1_qkv(
    const unsigned short* __restrict__ XT,
    const unsigned short* __restrict__ WQ, const float* __restrict__ bq,
    const unsigned short* __restrict__ WK, const float* __restrict__ bk,
    const unsigned short* __restrict__ WV, const float* __restrict__ bv,
    unsigned short* __restrict__ QT, unsigned short* __restrict__ KT,
    unsigned short* __restrict__ V) {
  int t = threadIdx.x, lane = t & 63, w = t >> 6, l15 = lane & 15, g = lane >> 4;
  int wg = blockIdx.x, b = wg >> 6, nb = wg & 63;
  int n0 = nb * 64;
  const unsigned short* xtb = XT + (size_t)b * N * C;
  const unsigned short* Ws[3] = {WQ, WK, WV};
  const float* Bs[3] = {bq, bk, bv};
#pragma unroll
  for (int np = 0; np < 2; ++np) {
    s16x8 xf[2][8];
#pragma unroll
    for (int n2 = 0; n2 < 2; ++n2)
#pragma unroll
      for (int cc = 0; cc < 8; ++cc)
        xf[n2][cc] = *(const s16x8*)(xtb + (size_t)(n0 + np * 32 + n2 * 16 + l15) * C + cc * 32 + g * 8);
#pragma unroll
    for (int ty = 0; ty < 3; ++ty) {
      float bsc = (ty == 0) ? 0.0625f : 1.0f;
#pragma unroll
      for (int ot = 0; ot < 4; ++ot) {
        int o0 = w * 64 + ot * 16;
        f32x4 bias = *(const f32x4*)(Bs[ty] + o0 + g * 4);
        s16x8 wf[8];
#pragma unroll
        for (int cc = 0; cc < 8; ++cc)
          wf[cc] = *(const s16x8*)(Ws[ty] + (size_t)(o0 + l15) * C + cc * 32 + g * 8);
#pragma unroll
        for (int n2 = 0; n2 < 2; ++n2) {
          f32x4 D = {0.f, 0.f, 0.f, 0.f};
#pragma unroll
          for (int cc = 0; cc < 8; ++cc) D = mfma16(wf[cc], xf[n2][cc], D);
          int n = n0 + np * 32 + n2 * 16 + l15;
          if (ty < 2) {
            s16x4 pk;
#pragma unroll
            for (int r = 0; r < 4; ++r) pk[r] = (short)f2bf(D[r] + bias[r] * bsc);
            unsigned short* dst = (ty == 0 ? QT : KT) + (size_t)b * N * C + (size_t)n * C + o0 + g * 4;
            *(s16x4*)dst = pk;
          } else {
#pragma unroll
            for (int r = 0; r < 4; ++r)
              V[(size_t)b * C * N + (size_t)(o0 + g * 4 + r) * N + n] = f2bf(D[r] + bias[r]);
          }
        }
      }
    }
  }
}

// ---------------- k2: Lp[s][b][j] = partial sum_i exp(S[i,j]-12) ----------------
// grid 512: jb = wg&31 (128 j), isplit = (wg>>5)&3 (1024 i), b = wg>>7.
__global__ __launch_bounds__(256, 2) void k2_stats(
    const unsigned short* __restrict__ QT, const unsigned short* __restrict__ KT,
    float* __restrict__ Lp) {
  int t = threadIdx.x, lane = t & 63, w = t >> 6, l15 = lane & 15, g = lane >> 4;
  int wg = blockIdx.x, jb = wg & 31, isplit = (wg >> 5) & 3, b = wg >> 7;
  const unsigned short* qtb = QT + (size_t)b * N * C;
  const unsigned short* ktb = KT + (size_t)b * N * C;
  s16x8 kf[2][8];
#pragma unroll
  for (int jt = 0; jt < 2; ++jt)
#pragma unroll
    for (int cc = 0; cc < 8; ++cc)
      kf[jt][cc] = *(const s16x8*)(ktb + (size_t)(jb * 128 + w * 32 + jt * 16 + l15) * C + cc * 32 + g * 8);
  float sums[2][4];
#pragma unroll
  for (int jt = 0; jt < 2; ++jt)
#pragma unroll
    for (int r = 0; r < 4; ++r) sums[jt][r] = 0.f;
  for (int it = 0; it < 64; ++it) {
    int i0 = isplit * 1024 + it * 16;
    f32x4 D0 = {0.f, 0.f, 0.f, 0.f}, D1 = {0.f, 0.f, 0.f, 0.f};
#pragma unroll
    for (int cc = 0; cc < 8; ++cc) {
      s16x8 qf = *(const s16x8*)(qtb + (size_t)(i0 + l15) * C + cc * 32 + g * 8);
      D0 = mfma16(kf[0][cc], qf, D0);
      D1 = mfma16(kf[1][cc], qf, D1);
    }
#pragma unroll
    for (int r = 0; r < 4; ++r) {
      sums[0][r] += __expf(D0[r] - 12.f);
      sums[1][r] += __expf(D1[r] - 12.f);
    }
  }
#pragma unroll
  for (int off = 1; off < 16; off <<= 1)
#pragma unroll
    for (int jt = 0; jt < 2; ++jt)
#pragma unroll
      for (int r = 0; r < 4; ++r) sums[jt][r] += __shfl_xor(sums[jt][r], off);
  if (l15 == 0) {
#pragma unroll
    for (int jt = 0; jt < 2; ++jt) {
      f32x4 o = {sums[jt][0], sums[jt][1], sums[jt][2], sums[jt][3]};
      *(f32x4*)&Lp[(size_t)(isplit * 4 + b) * N + jb * 128 + w * 32 + jt * 16 + g * 4] = o;
    }
  }
}

// ---------------- k2c: R[b][j] = 1 / sum_s Lp[s][b][j] ----------------
__global__ __launch_bounds__(256) void k2c_recip(const float* __restrict__ Lp,
                                                 float* __restrict__ R) {
  int idx = (blockIdx.x * 256 + threadIdx.x) * 4;  // over B*N = 16384
  int b = idx >> 12, n = idx & (N - 1);
  f32x4 s = *(const f32x4*)(Lp + (size_t)b * N + n);
#pragma unroll
  for (int sl = 1; sl < 4; ++sl) {
    f32x4 l2 = *(const f32x4*)(Lp + (size_t)(sl * 4 + b) * N + n);
#pragma unroll
    for (int e = 0; e < 4; ++e) s[e] += l2[e];
  }
  f32x4 o;
#pragma unroll
  for (int e = 0; e < 4; ++e) o[e] = 1.0f / s[e];
  *(f32x4*)(R + idx) = o;
}

// ---------------- k3: producer/consumer flash attention (32x32 MFMA) ----------------
// grid 256 x 512 threads. x = wg&7 -> XCD slot: b = x>>1, ihalf = x&1;
// ib = ihalf*32 + (wg>>3); block owns i0 = ib*64 .. +64, sweeps 4096 j in 64 phases.
// Waves 0-3 (QK): wave w: j-tile jt=w&1, i-tile it=(w>>1)&1; Q B-frags in regs.
// Waves 4-7 (PV): wave pw=w-4: c-tiles {2pw, 2pw+1} x i-tiles {0,1}; lags one phase.
// K_lds single-buf (stage K(p+1) post-barrier), V_lds single-buf (stage V(p)),
// P_lds double-buffered. All LDS strides 9 or 33 x16B -> conflict-free frag access;
// staging: thread stages chunk (t + 256k): coalesced global + distinct bank-quads.
__global__ __launch_bounds__(512, 2) void k3_attn(
    const unsigned short* __restrict__ QT, const unsigned short* __restrict__ KT,
    const unsigned short* __restrict__ V, const float* __restrict__ R,
    float* __restrict__ OT) {
  __shared__ short K_lds[64 * 264];      // [64 j][256 c + 8]   33.8 KB
  __shared__ short V_lds[256 * 72];      // [256 c][64 j + 8]   36.9 KB
  __shared__ short P_lds[2][64 * 72];    // [buf][64 i][64 j+8] 18.4 KB
  int t = threadIdx.x, lane = t & 63, w = t >> 6;
  int l31 = lane & 31, h = lane >> 5;
  int wg = blockIdx.x;
  int x = wg & 7, b = x >> 1, ib = (x & 1) * 32 + (wg >> 3);
  int i0 = ib * 64;
  const unsigned short* qtb = QT + (size_t)b * N * C;
  const unsigned short* ktb = KT + (size_t)b * N * C;
  const unsigned short* vb = V + (size_t)b * C * N;
  const float* rb = R + (size_t)b * N;
  float* otb = OT + (size_t)b * N * C;
  bool isQK = (w < 4);
  int jt = w & 1, it = (w >> 1) & 1;   // QK params
  int pw = w & 3, ct0 = pw * 2;        // PV params (w-4 -> w&3 for w in 4..7)
  int u = t & 255;

  s16x8 qf[16];
  f32x16 acc00, acc01, acc10, acc11;
  if (isQK) {
#pragma unroll
    for (int kk = 0; kk < 16; ++kk)
      qf[kk] = *(const s16x8*)(qtb + (size_t)(i0 + it * 32 + l31) * C + kk * 16 + h * 8);
    // stage K(0): thread u handles chunks u + 256k -> row (u>>5)+8k, col16 (u&31)
#pragma unroll
    for (int k = 0; k < 8; ++k) {
      int kr = (u >> 5) + 8 * k;
      f32x4 kv = *(const f32x4*)(ktb + (size_t)kr * C + (u & 31) * 8);
      *(f32x4*)&K_lds[kr * 264 + (u & 31) * 8] = kv;
    }
  } else {
    acc00 = zero16(); acc01 = zero16(); acc10 = zero16(); acc11 = zero16();
  }
  __syncthreads();

  for (int p = 0; p <= 64; ++p) {
    int J0 = p << 6;
    f32x4 kreg[8], vreg[8];
    // issue staging loads early (land under compute)
    if (isQK) {
      if (p < 63) {
        int J1 = J0 + 64;
#pragma unroll
        for (int k = 0; k < 8; ++k)
          kreg[k] = *(const f32x4*)(ktb + (size_t)(J1 + (u >> 5) + 8 * k) * C + (u & 31) * 8);
      }
    } else {
      if (p < 64) {
#pragma unroll
        for (int k = 0; k < 8; ++k)
          vreg[k] = *(const f32x4*)(vb + (size_t)((u >> 3) + 32 * k) * N + J0 + (u & 7) * 8);
      }
    }
    // compute
    if (isQK) {
      if (p < 64) {
        f32x16 Da = zero16(), Db = zero16();
        const short* kbase = &K_lds[(jt * 32 + l31) * 264 + h * 8];
#pragma unroll
        for (int kk = 0; kk < 16; kk += 2) {
          s16x8 ka = *(const s16x8*)(kbase + kk * 16);
          s16x8 kb2 = *(const s16x8*)(kbase + kk * 16 + 16);
          Da = mfma32(ka, qf[kk], Da);
          Db = mfma32(kb2, qf[kk + 1], Db);
        }
        const float* rp = rb + J0 + jt * 32 + h * 4;
        short* pb = &P_lds[p & 1][(it * 32 + l31) * 72 + jt * 32 + h * 4];
#pragma unroll
        for (int q = 0; q < 4; ++q) {
          f32x4 r4 = *(const f32x4*)(rp + q * 8);
          s16x4 pk;
#pragma unroll
          for (int e = 0; e < 4; ++e)
            pk[e] = (short)f2bf(__expf(Da[q * 4 + e] + Db[q * 4 + e] - 12.f) * r4[e]);
          *(s16x4*)(pb + q * 8) = pk;
        }
      }
    } else {
      if (p >= 1) {
        const short* pbase = &P_lds[(p - 1) & 1][l31 * 72 + h * 8];
        const short* vbase = &V_lds[(ct0 * 32 + l31) * 72 + h * 8];
#pragma unroll
        for (int kk = 0; kk < 4; ++kk) {
          s16x8 vf0 = *(const s16x8*)(vbase + kk * 16);
          s16x8 vf1 = *(const s16x8*)(vbase + 32 * 72 + kk * 16);
          s16x8 pf0 = *(const s16x8*)(pbase + kk * 16);
          s16x8 pf1 = *(const s16x8*)(pbase + 32 * 72 + kk * 16);
          acc00 = mfma32(vf0, pf0, acc00);
          acc01 = mfma32(vf0, pf1, acc01);
          acc10 = mfma32(vf1, pf0, acc10);
          acc11 = mfma32(vf1, pf1, acc11);
        }
      }
    }
    __syncthreads();
    // staging writes
    if (isQK) {
      if (p < 63) {
#pragma unroll
        for (int k = 0; k < 8; ++k)
          *(f32x4*)&K_lds[((u >> 5) + 8 * k) * 264 + (u & 31) * 8] = kreg[k];
      }
    } else {
      if (p < 64) {
#pragma unroll
        for (int k = 0; k < 8; ++k)
          *(f32x4*)&V_lds[((u >> 3) + 32 * k) * 72 + (u & 7) * 8] = vreg[k];
      }
    }
    __syncthreads();
  }

  if (!isQK) {
    // D map: col=l31 (i-within-tile), row = (reg&3)+8*(reg>>2)+4h (c-within-tile)
#pragma unroll
    for (int q = 0; q < 4; ++q) {
      f32x4 o;
      o[0] = acc00[q * 4 + 0]; o[1] = acc00[q * 4 + 1]; o[2] = acc00[q * 4 + 2]; o[3] = acc00[q * 4 + 3];
      *(f32x4*)&otb[(size_t)(i0 + l31) * C + ct0 * 32 + q * 8 + h * 4] = o;
      o[0] = acc01[q * 4 + 0]; o[1] = acc01[q * 4 + 1]; o[2] = acc01[q * 4 + 2]; o[3] = acc01[q * 4 + 3];
      *(f32x4*)&otb[(size_t)(i0 + 32 + l31) * C + ct0 * 32 + q * 8 + h * 4] = o;
      o[0] = acc10[q * 4 + 0]; o[1] = acc10[q * 4 + 1]; o[2] = acc10[q * 4 + 2]; o[3] = acc10[q * 4 + 3];
      *(f32x4*)&otb[(size_t)(i0 + l31) * C + (ct0 + 1) * 32 + q * 8 + h * 4] = o;
      o[0] = acc11[q * 4 + 0]; o[1] = acc11[q * 4 + 1]; o[2] = acc11[q * 4 + 2]; o[3] = acc11[q * 4 + 3];
      *(f32x4*)&otb[(size_t)(i0 + 32 + l31) * C + (ct0 + 1) * 32 + q * 8 + h * 4] = o;
    }
  }
}

// ---------------- k4: proj with split-bf16 (hi/lo), pre-split weights ----------------
__global__ __launch_bounds__(256) void k4_proj(const float* __restrict__ OT,
                                               const unsigned short* __restrict__ WPH,
                                               const unsigned short* __restrict__ WPL,
                                               const float* __restrict__ bp,
                                               float* __restrict__ OUT) {
  int t = threadIdx.x, lane = t & 63, w = t >> 6, l15 = lane & 15, g = lane >> 4;
  int wg = blockIdx.x, b = wg >> 6, nb = wg & 63;
  const float* otb = OT + (size_t)b * N * C;
  float* ob = OUT + (size_t)b * (size_t)C * N;
  for (int nt = 0; nt < 4; ++nt) {
    s16x8 xh[8], xl[8];
#pragma unroll
    for (int cc = 0; cc < 8; ++cc) {
      const float* p = otb + (size_t)(nb * 64 + nt * 16 + l15) * C + cc * 32 + g * 8;
      f32x4 a = *(const f32x4*)p;
      f32x4 b2 = *(const f32x4*)(p + 4);
      s16x8 h, lo;
#pragma unroll
      for (int e = 0; e < 4; ++e) {
        unsigned short hh = f2bf(a[e]); h[e] = (short)hh; lo[e] = (short)f2bf(a[e] - bf2f(hh));
        unsigned short h2 = f2bf(b2[e]); h[e + 4] = (short)h2; lo[e + 4] = (short)f2bf(b2[e] - bf2f(h2));
      }
      xh[cc] = h; xl[cc] = lo;
    }
#pragma unroll
    for (int ot = 0; ot < 4; ++ot) {
      int o0 = w * 64 + ot * 16;
      f32x4 bias = *(const f32x4*)(bp + o0 + g * 4);
      f32x4 D = {0.f, 0.f, 0.f, 0.f};
#pragma unroll
      for (int cc = 0; cc < 8; ++cc) {
        s16x8 h = *(const s16x8*)(WPH + (size_t)(o0 + l15) * C + cc * 32 + g * 8);
        s16x8 lo = *(const s16x8*)(WPL + (size_t)(o0 + l15) * C + cc * 32 + g * 8);
        D = mfma16(h, xh[cc], D);
        D = mfma16(h, xl[cc], D);
        D = mfma16(lo, xh[cc], D);
      }
#pragma unroll
      for (int r = 0; r < 4; ++r)
        ob[(size_t)(o0 + g * 4 + r) * N + nb * 64 + nt * 16 + l15] = D[r] + bias[r];
    }
  }
}

extern "C" void kernel_launch(void* const* d_in, const int* in_sizes, int n_in,
                              void* d_out, int out_size, void* d_ws, size_t ws_size,
                              hipStream_t stream) {
  const float* x = (const float*)d_in[0];
  const float* wq = (const float*)d_in[1];
  const float* bq = (const float*)d_in[2];
  const float* wk = (const float*)d_in[3];
  const float* bk = (const float*)d_in[4];
  const float* wv = (const float*)d_in[5];
  const float* bv = (const float*)d_in[6];
  const float* wp = (const float*)d_in[7];
  const float* bp = (const float*)d_in[8];
  float* out = (float*)d_out;
  char* ws = (char*)d_ws;
  // workspace layout (~42 MB; XT/OT overlap — XT dead after k1):
  unsigned short* QT = (unsigned short*)(ws + 0);          //  8 MB bf16 [B][N][C] (pre-scaled /16)
  unsigned short* KT = (unsigned short*)(ws + 8388608);    //  8 MB bf16 [B][N][C]
  unsigned short* V  = (unsigned short*)(ws + 16777216);   //  8 MB bf16 [B][C][N]
  unsigned short* WQ = (unsigned short*)(ws + 25165824);   // 128 KB each
  unsigned short* WK = (unsigned short*)(ws + 25296896);
  unsigned short* WV = (unsigned short*)(ws + 25427968);
  unsigned short* WPH = (unsigned short*)(ws + 25559040);
  unsigned short* WPL = (unsigned short*)(ws + 25690112);
  float* Lp = (float*)(ws + 25821184);                     // 256 KB f32 [4][B][N]
  float* R  = (float*)(ws + 26083328);                     //  64 KB f32 [B][N]
  unsigned short* XT = (unsigned short*)(ws + 26214400);   //  8 MB bf16 (k0..k1 only)
  float* OT = (float*)(ws + 26214400);                     // 16 MB f32 (after k1)

  hipLaunchKernelGGL(kw_conv, dim3(64), dim3(256), 0, stream, wq, wk, wv, wp, WQ, WK, WV, WPH, WPL);
  hipLaunchKernelGGL(k0_transpose, dim3(1024), dim3(256), 0, stream, x, XT);
  hipLaunchKernelGGL(k1_qkv, dim3(256), dim3(256), 0, stream, XT, WQ, bq, WK, bk, WV, bv, QT, KT, V);
  hipLaunchKernelGGL(k2_stats, dim3(512), dim3(256), 0, stream, QT, KT, Lp);
  hipLaunchKernelGGL(k2c_recip, dim3(16), dim3(256), 0, stream, Lp, R);
  hipLaunchKernelGGL(k3_attn, dim3(256), dim3(512), 0, stream, QT, KT, V, R, OT);
  hipLaunchKernelGGL(k4_proj, dim3(256), dim3(256), 0, stream, OT, WPH, WPL, bp, out);
}